// Round 12
// baseline (5512.283 us; speedup 1.0000x reference)
//
#include <hip/hip_runtime.h>
#include <cstdint>

typedef _Float16 f16;
typedef _Float16 f16x8 __attribute__((ext_vector_type(8)));
typedef float f32x4 __attribute__((ext_vector_type(4)));
typedef unsigned u32;

#define DI static __device__ __forceinline__

constexpr int T = 512, H = 512, Osz = 10;
constexpr int NWG = 256, NTH = 768;      // 12 waves per WG
constexpr int GW = 32;                   // WGs serving each group
constexpr int GB = 4;                    // batch rows per group (16 groups)
constexpr int BH = 64 * H;               // f16 elems per h-buffer parity (all rows)
constexpr size_t XH_OFF = 512 * 1024;    // ws byte offset of f16 x copy

struct __align__(256) GSync { u32 cnt[2]; u32 epoch; u32 pad[61]; };

DI float sigf(float x)   { return 1.f / (1.f + __expf(-x)); }
DI float tanhf_(float x) { return 1.f - 2.f / (__expf(2.f * x) + 1.f); }

DI f16x8 cvt8(const float* p) {
  f16x8 r;
#pragma unroll
  for (int j = 0; j < 8; ++j) r[j] = (f16)p[j];
  return r;
}

DI void pin8(f16x8& v) { asm volatile("" : "+v"(v)); }

// Device-scope (LLC) stores: write-through past L1/L2.
DI void st16_sc1(void* p, f16 v) {
  asm volatile("global_store_short %0, %1, off sc1" :: "v"(p), "v"(v));
}
DI void st32_sc1(void* p, u32 v) {
  asm volatile("global_store_dword %0, %1, off sc1" :: "v"(p), "v"(v));
}
DI void st128_sc1(void* p, f16x8 v) {
  asm volatile("global_store_dwordx4 %0, %1, off sc1" :: "v"(p), "v"(v));
}
DI void vm_drain() { asm volatile("s_waitcnt vmcnt(0)" ::: "memory"); }

// One device-scope 16B load (stage: 1 slot per thread now).
DI f16x8 ld1_sc1(const void* p) {
  f16x8 a;
  asm volatile("global_load_dwordx4 %0, %1, off sc1\n\ts_waitcnt vmcnt(0)"
               : "=v"(a) : "v"(p) : "memory");
  return a;
}

// 8 device-scope 16B loads (stride 16B) — one 128B row chunk (FC epilogue).
DI void ldrow8(const f16* base, f16x8* A) {
  asm volatile(
    "global_load_dwordx4 %0, %8, off sc1\n\t"
    "global_load_dwordx4 %1, %8, off offset:16 sc1\n\t"
    "global_load_dwordx4 %2, %8, off offset:32 sc1\n\t"
    "global_load_dwordx4 %3, %8, off offset:48 sc1\n\t"
    "global_load_dwordx4 %4, %8, off offset:64 sc1\n\t"
    "global_load_dwordx4 %5, %8, off offset:80 sc1\n\t"
    "global_load_dwordx4 %6, %8, off offset:96 sc1\n\t"
    "global_load_dwordx4 %7, %8, off offset:112 sc1\n\t"
    "s_waitcnt vmcnt(0)"
    : "=&v"(A[0]), "=&v"(A[1]), "=&v"(A[2]), "=&v"(A[3]),
      "=&v"(A[4]), "=&v"(A[5]), "=&v"(A[6]), "=&v"(A[7])
    : "v"(base)
    : "memory");
}

// r8-proven barrier semantics, split into arrive / wait so another group's
// work can sit between them (latency hiding).
DI void g_arrive(GSync* g, u32 idx, int tid) {
  __syncthreads();                       // all P-reads done, combine drained
  if (tid == 0) {
    u32 old = __hip_atomic_fetch_add(&g->cnt[idx & 1], 1u,
                                     __ATOMIC_RELAXED, __HIP_MEMORY_SCOPE_AGENT);
    if (old == GW - 1) {
      __hip_atomic_store(&g->cnt[idx & 1], 0u, __ATOMIC_RELAXED, __HIP_MEMORY_SCOPE_AGENT);
      __hip_atomic_store(&g->epoch, idx + 1, __ATOMIC_RELAXED, __HIP_MEMORY_SCOPE_AGENT);
    }
  }
}
DI void g_wait(GSync* g, u32 idx, int tid) {
  if (tid == 0) {
    u32 spins = 0;
    while (__hip_atomic_load(&g->epoch, __ATOMIC_RELAXED, __HIP_MEMORY_SCOPE_AGENT) < idx + 1u) {
      __builtin_amdgcn_s_sleep(1);
      if (++spins > 1000000u) break;     // GPU-hang insurance only
    }
  }
  __syncthreads();
}

__global__ __launch_bounds__(NTH, 1) void rnn_all(
    const float* __restrict__ x,
    const float* __restrict__ lwih, const float* __restrict__ lwhh,
    const float* __restrict__ lbih, const float* __restrict__ lbhh,
    const float* __restrict__ gwih, const float* __restrict__ gwhh,
    const float* __restrict__ gbih, const float* __restrict__ gbhh,
    const float* __restrict__ rwih, const float* __restrict__ rwhh,
    const float* __restrict__ rbih, const float* __restrict__ rbhh,
    const float* __restrict__ fcw, const float* __restrict__ fcb,
    float* __restrict__ out, char* __restrict__ ws)
{
  // Per-group staged h: 3 bufs x 4 rows x 64 16B-slots, XOR-swizzled by row.
  __shared__ __align__(16) u32 HSA[3 * 1024];   // 12 KB (group A)
  __shared__ __align__(16) u32 HSB[3 * 1024];   // 12 KB (group B)
  __shared__ float P[12][16][20];               // C fragments (shared A/B in time)
  __shared__ float sb[16][11];                  // biases per owned column

  const int tid  = threadIdx.x;
  const int bid  = blockIdx.x;
  const int grpA = bid & 7;         // groups 0..7  (rows 0..31)
  const int grpB = grpA + 8;        // groups 8..15 (rows 32..63)
  const int w32  = bid >> 3;        // col slice owner (16 cols)
  const int bg0A = grpA * GB;
  const int bg0B = grpB * GB;
  const int col0 = w32 * 16;
  const int w    = tid >> 6;
  const int lane = tid & 63;
  const int ln   = lane & 15;
  const int lk   = lane >> 4;

  GSync* gsA = reinterpret_cast<GSync*>(ws) + grpA;
  GSync* gsB = reinterpret_cast<GSync*>(ws) + grpB;
  f16* HB = reinterpret_cast<f16*>(ws + 4096);            // HL|HG|HR, 2*BH each
  f16* xh = reinterpret_cast<f16*>(ws + XH_OFF);          // [64][T][256] f16

  // ---- W fragments (SHARED by groups A and B — same columns) ----
  // waves 0-3: LSTM i,f,g,o (K=512 hh + 256 ih(x)); 4-6: GRU w_ih; 7-9: GRU w_hh;
  // 10: RNN w_hh; 11: RNN w_ih
  f16x8 Bw[24];
#pragma unroll
  for (int ks = 16; ks < 24; ++ks) Bw[ks] = (f16x8)(f16)0.f;
  if (w < 4) {
    const int row = w * 512 + col0 + ln;
    const float* ph  = lwhh + (size_t)row * 512 + lk * 8;
    const float* px2 = lwih + (size_t)row * 256 + lk * 8;
#pragma unroll
    for (int ks = 0; ks < 16; ++ks) Bw[ks] = cvt8(ph + ks * 32);
#pragma unroll
    for (int ks = 0; ks < 8;  ++ks) Bw[16 + ks] = cvt8(px2 + ks * 32);
  } else if (w < 7) {
    const int row = (w - 4) * 512 + col0 + ln;
    const float* p = gwih + (size_t)row * 512 + lk * 8;
#pragma unroll
    for (int ks = 0; ks < 16; ++ks) Bw[ks] = cvt8(p + ks * 32);
  } else if (w < 10) {
    const int row = (w - 7) * 512 + col0 + ln;
    const float* p = gwhh + (size_t)row * 512 + lk * 8;
#pragma unroll
    for (int ks = 0; ks < 16; ++ks) Bw[ks] = cvt8(p + ks * 32);
  } else if (w == 10) {
    const float* p = rwhh + (size_t)(col0 + ln) * 512 + lk * 8;
#pragma unroll
    for (int ks = 0; ks < 16; ++ks) Bw[ks] = cvt8(p + ks * 32);
  } else {
    const float* p = rwih + (size_t)(col0 + ln) * 512 + lk * 8;
#pragma unroll
    for (int ks = 0; ks < 16; ++ks) Bw[ks] = cvt8(p + ks * 32);
  }
#pragma unroll
  for (int ks = 0; ks < 24; ++ks) pin8(Bw[ks]);

  // ---- biases -> LDS ----
  for (int i = tid; i < 16 * 11; i += NTH) {
    int c = i / 11, j = i % 11, col = col0 + c;
    float v;
    if (j < 4)       v = lbih[j * 512 + col] + lbhh[j * 512 + col];
    else if (j < 7)  v = gbih[(j - 4) * 512 + col];
    else if (j < 10) v = gbhh[(j - 7) * 512 + col];
    else             v = rbih[col] + rbhh[col];
    sb[c][j] = v;
  }

  // ---- prologue (sc1, one drain): flat x->f16 copy + flat h zero ----
  {
    const int g0 = bid * NTH + tid;
    for (int c = g0; c < 64 * T * 256 / 8; c += NWG * NTH) {
      f16x8 v = cvt8(x + (size_t)c * 8);
      st128_sc1((void*)(xh + (size_t)c * 8), v);
    }
    if (g0 < 3 * 2 * BH / 2)
      st32_sc1((void*)(reinterpret_cast<u32*>(HB) + g0), 0u);
  }
  vm_drain();
  g_arrive(gsA, 0u, tid);
  g_arrive(gsB, 0u, tid);

  // per-combine-thread recurrent state (tid < 64; one (row,col) per group)
  float cregA = 0.f, hgregA = 0.f, cregB = 0.f, hgregB = 0.f;

  const int hbuf = (w < 7) ? 0 : ((w == 10) ? 2 : 1);

  // Hoisted stage addressing: thread -> (buf, row, slot); 768 slots = 12 KB
  const int sb0 = tid >> 8;            // 0..2 buffer
  const int sr_ = tid & 255;
  const int srow = sr_ >> 6;           // 0..3 row-in-group
  const int sslt = sr_ & 63;           // 0..63 16B slot
  const size_t stg_off = (size_t)sb0 * 2 * BH + (size_t)srow * H + sslt * 8;
  const u32 lds_off = (u32)((sb0 << 10) + srow * 256 + ((sslt ^ srow) << 2));

  const u32 rw_ = (u32)(ln & 3);
  const u32 abase = (u32)hbuf * 1024u + rw_ * 256u;

  // One phase = {wait, stage, mfma, combine, arrive} for one group.
  auto do_phase = [&](u32* HSu, GSync* gs, const int bg0,
                      float& creg, float& hgreg, const int s) {
    const int cur = s & 1, prev = cur ^ 1;
    const int sc = (s < T) ? s : (T - 1);

    g_wait(gs, (u32)s, tid);             // h(s-1) of this group visible

    // STAGE: 12KB, one 16B slot per thread
    {
      const f16* p0 = HB + stg_off + (size_t)prev * BH + (size_t)bg0 * H;
      *reinterpret_cast<f16x8*>(&HSu[lds_off]) = ld1_sc1(p0);
    }
    __syncthreads();

    // MFMA: issue x loads (waves 0-3), h-MFMAs from LDS, then x-MFMAs
    f32x4 acc = {0.f, 0.f, 0.f, 0.f};
    f16x8 xa[8];
    if (w < 4) {
      const f16* px = xh + ((size_t)(bg0 + (ln & 3)) * T + sc) * 256 + lk * 8;
#pragma unroll
      for (int ks = 0; ks < 8; ++ks)
        xa[ks] = *reinterpret_cast<const f16x8*>(px + ks * 32);
    }
#pragma unroll
    for (int ks = 0; ks < 16; ++ks) {
      const f16x8 a = *reinterpret_cast<const f16x8*>(
          &HSu[abase + ((((u32)(ks * 4 + lk)) ^ rw_) << 2)]);
      acc = __builtin_amdgcn_mfma_f32_16x16x32_f16(a, Bw[ks], acc, 0, 0, 0);
    }
    if (w < 4) {
#pragma unroll
      for (int ks = 0; ks < 8; ++ks)
        acc = __builtin_amdgcn_mfma_f32_16x16x32_f16(xa[ks], Bw[16 + ks], acc, 0, 0, 0);
    }
    if (lk == 0)   // rows 0..3 are the real batch rows
      *reinterpret_cast<f32x4*>(&P[w][ln][0]) = acc;
    __syncthreads();

    // COMBINE: 64 threads, one (row,col) each — same chain length as r8
    if (tid < 64) {
      const int cb = tid >> 4, cc = tid & 15;
      const int gb = bg0 + cb, col = col0 + cc;

      float iL = sigf(P[0][cc][cb] + sb[cc][0]);
      float fL = sigf(P[1][cc][cb] + sb[cc][1]);
      float gL = tanhf_(P[2][cc][cb] + sb[cc][2]);
      float oL = sigf(P[3][cc][cb] + sb[cc][3]);
      float cn = fL * creg + iL * gL;
      float hLv = oL * tanhf_(cn);
      float xr = P[4][cc][cb] + sb[cc][4];
      float xz = P[5][cc][cb] + sb[cc][5];
      float xn = P[6][cc][cb] + sb[cc][6];
      float hr = P[7][cc][cb] + sb[cc][7];
      float hz = P[8][cc][cb] + sb[cc][8];
      float hn = P[9][cc][cb] + sb[cc][9];
      float rg = sigf(xr + hr), zg = sigf(xz + hz);
      float ng = tanhf_(xn + rg * hn);
      float hGv = (1.f - zg) * ng + zg * hgreg;   // hgreg == h_gru(s-2)
      float hRv = tanhf_(P[10][cc][cb] + P[11][cc][cb] + sb[cc][10]);

      f16* rowp = HB + (size_t)cur * BH + (size_t)gb * H + col;
      if (s < T)            { creg = cn; st16_sc1((void*)rowp, (f16)hLv); }
      if (s >= 1 && s <= T) { hgreg = hGv; st16_sc1((void*)(rowp + 2 * BH), (f16)hGv); }
      if (s >= 2)           st16_sc1((void*)(rowp + 4 * BH), (f16)hRv);
      vm_drain();   // h visible at LLC before arrive
    }
    g_arrive(gs, (u32)(s + 1), tid);
  };

#pragma unroll 1
  for (int s = 0; s <= T + 1; ++s) {
    do_phase(HSA, gsA, bg0A, cregA, hgregA, s);   // A's barrier latency hides
    do_phase(HSB, gsB, bg0B, cregB, hgregB, s);   // under B's work, and v.v.
  }

  // ---- FC epilogue: bid<8 handles its two groups' 8 rows ----
  g_wait(gsA, (u32)(T + 2), tid);
  g_wait(gsB, (u32)(T + 2), tid);
  if (w32 == 0 && tid < 640) {
    const f16* hlast = HB + 4 * BH + BH;   // HR, parity 1 ( (T+1)&1 )
    int bo = tid >> 3, kq = tid & 7;
    int bl = bo / 10, o = bo % 10;
    int row = (bl < 4) ? (bg0A + bl) : (bg0B + bl - 4);
    const f16* ph = hlast + (size_t)row * H + kq * 64;
    const float* pw = fcw + (size_t)o * H + kq * 64;
    f16x8 v[8];
    ldrow8(ph, v);
    float a = 0.f;
#pragma unroll
    for (int q = 0; q < 8; ++q)
#pragma unroll
      for (int j = 0; j < 8; ++j) a += (float)v[q][j] * pw[q * 8 + j];
    a += __shfl_xor(a, 1);
    a += __shfl_xor(a, 2);
    a += __shfl_xor(a, 4);
    if (kq == 0) out[row * Osz + o] = a + fcb[o];
  }
}

extern "C" void kernel_launch(void* const* d_in, const int* in_sizes, int n_in,
                              void* d_out, int out_size, void* d_ws, size_t ws_size,
                              hipStream_t stream) {
  (void)in_sizes; (void)n_in; (void)out_size; (void)ws_size;
  const float* x    = (const float*)d_in[0];
  const float* lwih = (const float*)d_in[1];
  const float* lwhh = (const float*)d_in[2];
  const float* lbih = (const float*)d_in[3];
  const float* lbhh = (const float*)d_in[4];
  const float* gwih = (const float*)d_in[5];
  const float* gwhh = (const float*)d_in[6];
  const float* gbih = (const float*)d_in[7];
  const float* gbhh = (const float*)d_in[8];
  const float* rwih = (const float*)d_in[9];
  const float* rwhh = (const float*)d_in[10];
  const float* rbih = (const float*)d_in[11];
  const float* rbhh = (const float*)d_in[12];
  const float* fcw  = (const float*)d_in[13];
  const float* fcb  = (const float*)d_in[14];
  float* outp = (float*)d_out;
  char* wsp   = (char*)d_ws;

  hipMemsetAsync(d_ws, 0, 4096, stream);  // 16 GSync structs per replay

  rnn_all<<<dim3(NWG), dim3(NTH), 0, stream>>>(
      x, lwih, lwhh, lbih, lbhh, gwih, gwhh, gbih, gbhh,
      rwih, rwhh, rbih, rbhh, fcw, fcb, outp, wsp);
}

// Round 15
// 2004.515 us; speedup vs baseline: 2.7499x; 2.7499x over previous
//
#include <hip/hip_runtime.h>
#include <cstdint>

typedef _Float16 f16;
typedef _Float16 f16x8 __attribute__((ext_vector_type(8)));
typedef float f32x4 __attribute__((ext_vector_type(4)));
typedef unsigned u32;

#define DI static __device__ __forceinline__

constexpr int T = 512, H = 512, Osz = 10;
constexpr int NWG = 256, NTH = 768;      // 12 waves per WG
constexpr int GW = 32;                   // WGs per batch-group
constexpr int GB = 8;                    // batch rows per group
constexpr int BH = 64 * H;               // f16 elements per h-buffer parity
constexpr size_t XH_OFF = 512 * 1024;    // ws byte offset of f16 x copy
constexpr int XH_GRP = 8 * T * 256;      // f16 elems per group slice

struct __align__(256) GSync { u32 cnt[2]; u32 epoch; u32 pad[61]; };

DI float sigf(float x)   { return 1.f / (1.f + __expf(-x)); }
DI float tanhf_(float x) { return 1.f - 2.f / (__expf(2.f * x) + 1.f); }

DI f16x8 cvt8(const float* p) {
  f16x8 r;
#pragma unroll
  for (int j = 0; j < 8; ++j) r[j] = (f16)p[j];
  return r;
}

// Opaque pass-through; weight fragments stay resident in the unified
// VGPR/AGPR file (r7 evidence: VALUBusy 3.2% => no per-step reconversion).
DI void pin8(f16x8& v) { asm volatile("" : "+v"(v)); }

// Device-scope (LLC) stores: write-through past L1/L2.
DI void st16_sc1(void* p, f16 v) {
  asm volatile("global_store_short %0, %1, off sc1" :: "v"(p), "v"(v));
}
DI void st32_sc1(void* p, u32 v) {
  asm volatile("global_store_dword %0, %1, off sc1" :: "v"(p), "v"(v));
}
DI void st128_sc1(void* p, f16x8 v) {
  asm volatile("global_store_dwordx4 %0, %1, off sc1" :: "v"(p), "v"(v));
}
DI void vm_drain() { asm volatile("s_waitcnt vmcnt(0)" ::: "memory"); }

// Two device-scope 16B loads, one waitcnt — h staging (LLC -> regs -> LDS).
DI void ld2_sc1(const void* p0, const void* p1, f16x8& a, f16x8& b) {
  asm volatile(
    "global_load_dwordx4 %0, %2, off sc1\n\t"
    "global_load_dwordx4 %1, %3, off sc1\n\t"
    "s_waitcnt vmcnt(0)"
    : "=&v"(a), "=&v"(b)
    : "v"(p0), "v"(p1)
    : "memory");
}

// 8 device-scope 16B loads (stride 16B) — one 128B row chunk (FC epilogue).
DI void ldrow8(const f16* base, f16x8* A) {
  asm volatile(
    "global_load_dwordx4 %0, %8, off sc1\n\t"
    "global_load_dwordx4 %1, %8, off offset:16 sc1\n\t"
    "global_load_dwordx4 %2, %8, off offset:32 sc1\n\t"
    "global_load_dwordx4 %3, %8, off offset:48 sc1\n\t"
    "global_load_dwordx4 %4, %8, off offset:64 sc1\n\t"
    "global_load_dwordx4 %5, %8, off offset:80 sc1\n\t"
    "global_load_dwordx4 %6, %8, off offset:96 sc1\n\t"
    "global_load_dwordx4 %7, %8, off offset:112 sc1\n\t"
    "s_waitcnt vmcnt(0)"
    : "=&v"(A[0]), "=&v"(A[1]), "=&v"(A[2]), "=&v"(A[3]),
      "=&v"(A[4]), "=&v"(A[5]), "=&v"(A[6]), "=&v"(A[7])
    : "v"(base)
    : "memory");
}

// Flat 32-wide barrier at LLC (relaxed agent atomics, rounds 2/5/6/7/8-proven).
DI void group_barrier(GSync* g, u32 idx, int tid) {
  __syncthreads();
  if (tid == 0) {
    u32 old = __hip_atomic_fetch_add(&g->cnt[idx & 1], 1u,
                                     __ATOMIC_RELAXED, __HIP_MEMORY_SCOPE_AGENT);
    if (old == GW - 1) {
      __hip_atomic_store(&g->cnt[idx & 1], 0u, __ATOMIC_RELAXED, __HIP_MEMORY_SCOPE_AGENT);
      __hip_atomic_store(&g->epoch, idx + 1, __ATOMIC_RELAXED, __HIP_MEMORY_SCOPE_AGENT);
    } else {
      u32 spins = 0;
      while (__hip_atomic_load(&g->epoch, __ATOMIC_RELAXED, __HIP_MEMORY_SCOPE_AGENT) < idx + 1u) {
        __builtin_amdgcn_s_sleep(1);
        if (++spins > 1000000u) break;   // GPU-hang insurance only
      }
    }
  }
  __syncthreads();
}

__global__ __launch_bounds__(NTH, 1) void rnn_all(
    const float* __restrict__ x,
    const float* __restrict__ lwih, const float* __restrict__ lwhh,
    const float* __restrict__ lbih, const float* __restrict__ lbhh,
    const float* __restrict__ gwih, const float* __restrict__ gwhh,
    const float* __restrict__ gbih, const float* __restrict__ gbhh,
    const float* __restrict__ rwih, const float* __restrict__ rwhh,
    const float* __restrict__ rbih, const float* __restrict__ rbhh,
    const float* __restrict__ fcw, const float* __restrict__ fcb,
    float* __restrict__ out, char* __restrict__ ws)
{
  // Staged prev-parity h: 3 bufs x 8 rows x 512 f16 (16B slots XOR-swizzled
  // by row; staging + frag addressing verified in rounds 2/8).
  __shared__ __align__(16) u32 HSu[3 * 2048];   // 24 KB
  __shared__ float P[12][16][20];               // C fragments, padded
  __shared__ float sb[16][11];                  // biases per owned column

  const int tid  = threadIdx.x;
  const int bid  = blockIdx.x;
  const int grp  = bid & 7;         // batch group (XCD-locality heuristic only)
  const int w32  = bid >> 3;        // WG index in group: owns 16 h-columns
  const int bg0  = grp * GB;
  const int col0 = w32 * 16;
  const int w    = tid >> 6;
  const int lane = tid & 63;
  const int ln   = lane & 15;
  const int lk   = lane >> 4;

  GSync* gs = reinterpret_cast<GSync*>(ws) + grp;
  f16* HB = reinterpret_cast<f16*>(ws + 4096);            // HL|HG|HR, 2*BH each
  f16* xh = reinterpret_cast<f16*>(ws + XH_OFF) + (size_t)grp * XH_GRP;

  // ---- W fragments -> registers/AGPRs (persist across all 514 steps) ----
  // waves 0-3: LSTM gates i,f,g,o (K=512 hh + 256 ih(x))
  // waves 4-6: GRU w_ih (input h_lstm); 7-9: GRU w_hh; 10: RNN w_hh; 11: RNN w_ih
  f16x8 Bw[24];
#pragma unroll
  for (int ks = 16; ks < 24; ++ks) Bw[ks] = (f16x8)(f16)0.f;
  if (w < 4) {
    const int row = w * 512 + col0 + ln;
    const float* ph  = lwhh + (size_t)row * 512 + lk * 8;
    const float* px2 = lwih + (size_t)row * 256 + lk * 8;
#pragma unroll
    for (int ks = 0; ks < 16; ++ks) Bw[ks] = cvt8(ph + ks * 32);
#pragma unroll
    for (int ks = 0; ks < 8;  ++ks) Bw[16 + ks] = cvt8(px2 + ks * 32);
  } else if (w < 7) {
    const int row = (w - 4) * 512 + col0 + ln;
    const float* p = gwih + (size_t)row * 512 + lk * 8;
#pragma unroll
    for (int ks = 0; ks < 16; ++ks) Bw[ks] = cvt8(p + ks * 32);
  } else if (w < 10) {
    const int row = (w - 7) * 512 + col0 + ln;
    const float* p = gwhh + (size_t)row * 512 + lk * 8;
#pragma unroll
    for (int ks = 0; ks < 16; ++ks) Bw[ks] = cvt8(p + ks * 32);
  } else if (w == 10) {
    const float* p = rwhh + (size_t)(col0 + ln) * 512 + lk * 8;
#pragma unroll
    for (int ks = 0; ks < 16; ++ks) Bw[ks] = cvt8(p + ks * 32);
  } else {
    const float* p = rwih + (size_t)(col0 + ln) * 512 + lk * 8;
#pragma unroll
    for (int ks = 0; ks < 16; ++ks) Bw[ks] = cvt8(p + ks * 32);
  }
#pragma unroll
  for (int ks = 0; ks < 24; ++ks) pin8(Bw[ks]);

  // ---- biases -> LDS ----
  for (int i = tid; i < 16 * 11; i += NTH) {
    int c = i / 11, j = i % 11, col = col0 + c;
    float v;
    if (j < 4)       v = lbih[j * 512 + col] + lbhh[j * 512 + col];
    else if (j < 7)  v = gbih[(j - 4) * 512 + col];
    else if (j < 10) v = gbhh[(j - 7) * 512 + col];
    else             v = rbih[col] + rbhh[col];
    sb[c][j] = v;
  }

  // ---- prologue writes (all sc1, one drain): x->f16 copy + h zero ----
  {
    const float* xg_ = x + (size_t)bg0 * (T * 256);
    for (int c = w32 * NTH + tid; c < XH_GRP / 8; c += GW * NTH) {
      const float* p = xg_ + (size_t)c * 8;
      f16x8 v;
#pragma unroll
      for (int j = 0; j < 8; ++j) v[j] = (f16)p[j];
      st128_sc1((void*)(xh + (size_t)c * 8), v);
    }
  }
  {
    int i = w32 * NTH + tid;             // 0..24575 across the group
    if (i < 12288) {                     // 3 bufs * 2 par * 8 rows * 256 u32
      int buf = i >> 12, r = i & 4095, par = r >> 11, row = (r >> 8) & 7, cu = r & 255;
      void* p = (void*)(HB + (size_t)buf * 2 * BH + (size_t)par * BH
                           + (size_t)(bg0 + row) * H + cu * 2);
      st32_sc1(p, 0u);
    }
  }
  vm_drain();

  group_barrier(gs, 0u, tid);

  // per-combine-thread recurrent state (tid < 128): cell c and h_gru(prev)
  float creg = 0.f, hgreg = 0.f;

  const int hbuf = (w < 7) ? 0 : ((w == 10) ? 2 : 1);
  const f16* xrow = xh + ((size_t)(ln & 7) << 17) + lk * 8;

#pragma unroll 1
  for (int s = 0; s <= T + 1; ++s) {
    const int cur = s & 1, prev = cur ^ 1;
    const int sc = (s < T) ? s : (T - 1);

    // ---- STAGE: prev-parity h (3 bufs, 24KB) -> LDS once per WG ----
    // Cuts LLC/fabric reads 8x vs per-wave direct loads (r7: 192KB -> 24KB/WG).
    {
      int s0 = tid, s1 = tid + NTH;      // 1536 16B slots total
      int b0 = s0 >> 9, r0 = s0 & 511, row0 = r0 >> 6, sr0 = r0 & 63;
      int b1 = s1 >> 9, r1 = s1 & 511, row1 = r1 >> 6, sr1 = r1 & 63;
      const f16* p0 = HB + (size_t)b0 * 2 * BH + (size_t)prev * BH
                         + (size_t)(bg0 + row0) * H + sr0 * 8;
      const f16* p1 = HB + (size_t)b1 * 2 * BH + (size_t)prev * BH
                         + (size_t)(bg0 + row1) * H + sr1 * 8;
      f16x8 va, vb;
      ld2_sc1(p0, p1, va, vb);
      *reinterpret_cast<f16x8*>(&HSu[(b0 << 11) + row0 * 256 + ((sr0 ^ row0) << 2)]) = va;
      *reinterpret_cast<f16x8*>(&HSu[(b1 << 11) + row1 * 256 + ((sr1 ^ row1) << 2)]) = vb;
    }
    __syncthreads();

    // ---- MFMA phase: A-frags from swizzled LDS ----
    const u32 rw_ = (u32)(ln & 7);
    const u32 abase = (u32)hbuf * 2048u + rw_ * 256u;

    f32x4 acc = {0.f, 0.f, 0.f, 0.f};
    if (w < 4) {
      // x-projection: f16 pre-converted, plain cached loads (read-only data)
      const f16* px = xrow + (size_t)sc * 256;
#pragma unroll
      for (int ks = 0; ks < 8; ++ks) {
        const f16x8 a = *reinterpret_cast<const f16x8*>(px + ks * 32);
        acc = __builtin_amdgcn_mfma_f32_16x16x32_f16(a, Bw[16 + ks], acc, 0, 0, 0);
      }
    }
#pragma unroll
    for (int ks = 0; ks < 16; ++ks) {
      const f16x8 a = *reinterpret_cast<const f16x8*>(
          &HSu[abase + ((((u32)(ks * 4 + lk)) ^ rw_) << 2)]);
      acc = __builtin_amdgcn_mfma_f32_16x16x32_f16(a, Bw[ks], acc, 0, 0, 0);
    }

    if (lk < 2)   // only batch rows 0..7 are real
      *reinterpret_cast<f32x4*>(&P[w][ln][lk * 4]) = acc;
    __syncthreads();

    // ---- combine: 128 threads, 1 column each, fp32 gate math ----
    if (tid < 128) {
      const int cb = tid >> 4, cc = tid & 15;
      const int gb = bg0 + cb, col = col0 + cc;

      float iL = sigf(P[0][cc][cb] + sb[cc][0]);
      float fL = sigf(P[1][cc][cb] + sb[cc][1]);
      float gL = tanhf_(P[2][cc][cb] + sb[cc][2]);
      float oL = sigf(P[3][cc][cb] + sb[cc][3]);
      float cn = fL * creg + iL * gL;
      float hLv = oL * tanhf_(cn);
      float xr = P[4][cc][cb] + sb[cc][4];
      float xz = P[5][cc][cb] + sb[cc][5];
      float xn = P[6][cc][cb] + sb[cc][6];
      float hr = P[7][cc][cb] + sb[cc][7];
      float hz = P[8][cc][cb] + sb[cc][8];
      float hn = P[9][cc][cb] + sb[cc][9];
      float rg = sigf(xr + hr), zg = sigf(xz + hz);
      float ng = tanhf_(xn + rg * hn);
      float hGv = (1.f - zg) * ng + zg * hgreg;   // hgreg == h_gru(s-2) this col
      float hRv = tanhf_(P[10][cc][cb] + P[11][cc][cb] + sb[cc][10]);

      f16* rowp = HB + (size_t)cur * BH + (size_t)gb * H + col;
      if (s < T)            { creg = cn; st16_sc1((void*)rowp, (f16)hLv); }
      if (s >= 1 && s <= T) { hgreg = hGv; st16_sc1((void*)(rowp + 2 * BH), (f16)hGv); }
      if (s >= 2)           st16_sc1((void*)(rowp + 4 * BH), (f16)hRv);
      vm_drain();   // h visible at LLC before barrier arrive
    }
    group_barrier(gs, (u32)(s + 1), tid);
  }

  // ---- FC epilogue: one WG per group; h_rnn(T-1) is HR parity 1 ----
  if (w32 == 0 && tid < 640) {
    const f16* hlast = HB + 4 * BH + BH;   // HR, parity 1
    int bo = tid >> 3, kq = tid & 7;
    int bl = bo / 10, o = bo % 10;
    const f16* ph = hlast + (size_t)(bg0 + bl) * H + kq * 64;
    const float* pw = fcw + (size_t)o * H + kq * 64;
    f16x8 v[8];
    ldrow8(ph, v);
    float a = 0.f;
#pragma unroll
    for (int q = 0; q < 8; ++q)
#pragma unroll
      for (int j = 0; j < 8; ++j) a += (float)v[q][j] * pw[q * 8 + j];
    a += __shfl_xor(a, 1);
    a += __shfl_xor(a, 2);
    a += __shfl_xor(a, 4);
    if (kq == 0) out[(bg0 + bl) * Osz + o] = a + fcb[o];
  }
}

extern "C" void kernel_launch(void* const* d_in, const int* in_sizes, int n_in,
                              void* d_out, int out_size, void* d_ws, size_t ws_size,
                              hipStream_t stream) {
  (void)in_sizes; (void)n_in; (void)out_size; (void)ws_size;
  const float* x    = (const float*)d_in[0];
  const float* lwih = (const float*)d_in[1];
  const float* lwhh = (const float*)d_in[2];
  const float* lbih = (const float*)d_in[3];
  const float* lbhh = (const float*)d_in[4];
  const float* gwih = (const float*)d_in[5];
  const float* gwhh = (const float*)d_in[6];
  const float* gbih = (const float*)d_in[7];
  const float* gbhh = (const float*)d_in[8];
  const float* rwih = (const float*)d_in[9];
  const float* rwhh = (const float*)d_in[10];
  const float* rbih = (const float*)d_in[11];
  const float* rbhh = (const float*)d_in[12];
  const float* fcw  = (const float*)d_in[13];
  const float* fcb  = (const float*)d_in[14];
  float* outp = (float*)d_out;
  char* wsp   = (char*)d_ws;

  hipMemsetAsync(d_ws, 0, 4096, stream);  // GSync structs per replay

  rnn_all<<<dim3(NWG), dim3(NTH), 0, stream>>>(
      x, lwih, lwhh, lbih, lbhh, gwih, gwhh, gbih, gbhh,
      rwih, rwhh, rbih, rbhh, fcw, fcb, outp, wsp);
}